// Round 6
// baseline (287.455 us; speedup 1.0000x reference)
//
#include <hip/hip_runtime.h>
#include <cstdint>

#define BB 2
#define NN 16384
#define MM 4096
#define CF 256
#define CT 128
#define CP 64
#define NPB 32      // query points per block (grid 1024 -> 4 blocks/CU)
#define CHUNK 2048  // ref points staged in LDS per pass (32 KB)

// All-FP32 fused kernel (inputs/outputs are float32 per the reference; the
// round-3 profile's WRITE_SIZE=57.5MB proved the fp32 path is what passed).
// Phase 1: exact 3-NN — numpy-bit-exact fp32 (contraction off, numpy
// association order, stable lower-index tie-break).
// Phase 2: gather-interpolate 384 channels + 64-channel skip copy.
// Layout: 8 groups x 32 lanes; each group owns 4 query points (P=4/lane),
// so one ds_read_b128 of a ref serves 4 (point,ref) pairs.
__global__ __launch_bounds__(256, 4) void fp_fused_kernel(
    const float* __restrict__ coords,      // [B,N,3]
    const float* __restrict__ ref_coords,  // [B,M,3]
    const float* __restrict__ refF,        // [B,256,M]
    const float* __restrict__ refT,        // [B,128,M]
    const float* __restrict__ pf,          // [B,64,N]
    float* __restrict__ out)               // [B,320,N] ++ [B,128,N]
{
#pragma clang fp contract(off)
    __shared__ float4 refs[CHUNK];      // 32 KB (x, y, z, rr)
    __shared__ int    s_idx[NPB * 3];
    __shared__ float  s_w[NPB * 3];

    const int tid = threadIdx.x;
    const int b   = blockIdx.y;
    const int n0  = blockIdx.x * NPB;

    const int h = tid >> 5;             // group 0..7 (owns 4 points)
    const int s = tid & 31;             // lane within group

    // ---------------- phase 1: 3-NN, 32 lanes x 4 points per group ----------
    float cx[4], cy[4], cz[4], cc[4];
    {
        const float* cbase = coords + ((size_t)b * NN + n0 + h * 4) * 3;
        #pragma unroll
        for (int p = 0; p < 4; ++p) {
            const float x = cbase[p * 3 + 0];
            const float y = cbase[p * 3 + 1];
            const float z = cbase[p * 3 + 2];
            cx[p] = x; cy[p] = y; cz[p] = z;
            cc[p] = (x * x + y * y) + z * z;     // numpy sum order
        }
    }

    float d0[4], d1[4], d2[4];
    int   i0[4], i1[4], i2[4];
    #pragma unroll
    for (int p = 0; p < 4; ++p) {
        d0[p] = INFINITY; d1[p] = INFINITY; d2[p] = INFINITY;
        i0[p] = 0; i1[p] = 0; i2[p] = 0;         // benign fallbacks
    }

    const float* rc = ref_coords + (size_t)b * MM * 3;

    for (int ch = 0; ch < MM / CHUNK; ++ch) {
        __syncthreads();                 // refs[] reuse guard
        for (int e = tid; e < CHUNK; e += 256) {
            const int j = ch * CHUNK + e;
            const float x = rc[3 * j + 0];
            const float y = rc[3 * j + 1];
            const float z = rc[3 * j + 2];
            refs[e] = make_float4(x, y, z, (x * x + y * y) + z * z);
        }
        __syncthreads();

        // lane scans e = s, s+32, ... ascending -> strict '<' keeps lowest idx
        for (int it = 0; it < CHUNK / 32; ++it) {
            const int e = s + (it << 5);
            const float4 r = refs[e];
            const int j = ch * CHUNK + e;
            #pragma unroll
            for (int p = 0; p < 4; ++p) {
                const float t  = (cx[p] * r.x + cy[p] * r.y) + cz[p] * r.z;
                const float dd = (cc[p] + r.w) - (t + t);    // (A+B)-2*dot
                const bool l2 = dd < d2[p];
                const bool l1 = dd < d1[p];
                const bool l0 = dd < d0[p];
                d2[p] = l2 ? (l1 ? d1[p] : dd) : d2[p];  i2[p] = l2 ? (l1 ? i1[p] : j) : i2[p];
                d1[p] = l1 ? (l0 ? d0[p] : dd) : d1[p];  i1[p] = l1 ? (l0 ? i0[p] : j) : i1[p];
                d0[p] = l0 ? dd : d0[p];                 i0[p] = l0 ? j : i0[p];
            }
        }
    }

    // lexicographic (d, idx) insert: lower index wins exact ties (stable top_k)
    auto ins = [](float& D0, float& D1, float& D2, int& I0, int& I1, int& I2,
                  float e, int f) {
        const bool l2 = (e < D2) || (e == D2 && f < I2);
        const bool l1 = (e < D1) || (e == D1 && f < I1);
        const bool l0 = (e < D0) || (e == D0 && f < I0);
        D2 = l2 ? (l1 ? D1 : e) : D2;  I2 = l2 ? (l1 ? I1 : f) : I2;
        D1 = l1 ? (l0 ? D0 : e) : D1;  I1 = l1 ? (l0 ? I0 : f) : I1;
        D0 = l0 ? e : D0;              I0 = l0 ? f : I0;
    };

    // butterfly across the 32 lanes of the group (xor<32 stays in-group)
    for (int off = 1; off < 32; off <<= 1) {
        #pragma unroll
        for (int p = 0; p < 4; ++p) {
            const float e0 = __shfl_xor(d0[p], off, 64);
            const float e1 = __shfl_xor(d1[p], off, 64);
            const float e2 = __shfl_xor(d2[p], off, 64);
            const int   f0 = __shfl_xor(i0[p], off, 64);
            const int   f1 = __shfl_xor(i1[p], off, 64);
            const int   f2 = __shfl_xor(i2[p], off, 64);
            ins(d0[p], d1[p], d2[p], i0[p], i1[p], i2[p], e0, f0);
            ins(d0[p], d1[p], d2[p], i0[p], i1[p], i2[p], e1, f1);
            ins(d0[p], d1[p], d2[p], i0[p], i1[p], i2[p], e2, f2);
        }
    }

    if (s == 0) {
        #pragma unroll
        for (int p = 0; p < 4; ++p) {
            float w0 = 1.0f / (d0[p] + 1e-8f);     // IEEE divs, numpy order
            float w1 = 1.0f / (d1[p] + 1e-8f);
            float w2 = 1.0f / (d2[p] + 1e-8f);
            const float sum = (w0 + w1) + w2;
            const int pl = h * 4 + p;
            s_idx[pl * 3 + 0] = i0[p];
            s_idx[pl * 3 + 1] = i1[p];
            s_idx[pl * 3 + 2] = i2[p];
            s_w[pl * 3 + 0] = w0 / sum;
            s_w[pl * 3 + 1] = w1 / sum;
            s_w[pl * 3 + 2] = w2 / sum;
        }
    }
    __syncthreads();

    // ---------------- phase 2: interpolate + concat ----------------
    // Lane s owns point n0+s; group h handles rows h, h+8, ... (448 rows).
    // Class boundaries (256, 320) are multiples of 8 -> uniform branches.
    auto clampi = [](int v) { return v < 0 ? 0 : (v > MM - 1 ? MM - 1 : v); };
    const int   ia0 = clampi(s_idx[s * 3 + 0]);
    const int   ia1 = clampi(s_idx[s * 3 + 1]);
    const int   ia2 = clampi(s_idx[s * 3 + 2]);
    const float wa0 = s_w[s * 3 + 0], wa1 = s_w[s * 3 + 1], wa2 = s_w[s * 3 + 2];

    const int n = n0 + s;
    const size_t outT_base = (size_t)BB * (CF + CP) * NN;

    for (int it = 0; it < (CF + CP + CT) / 8; ++it) {
        const int row = it * 8 + h;
        if (row < CF) {
            const float* src = refF + ((size_t)b * CF + row) * MM;
            float* dst = out + ((size_t)b * (CF + CP) + row) * NN;
            const float v = (wa0 * src[ia0] + wa1 * src[ia1]) + wa2 * src[ia2];
            dst[n] = v;
        } else if (row < CF + CP) {
            const float* src = pf + ((size_t)b * CP + (row - CF)) * NN;
            float* dst = out + ((size_t)b * (CF + CP) + row) * NN;
            dst[n] = src[n];
        } else {
            const int tr = row - (CF + CP);
            const float* src = refT + ((size_t)b * CT + tr) * MM;
            float* dst = out + outT_base + ((size_t)b * CT + tr) * NN;
            const float v = (wa0 * src[ia0] + wa1 * src[ia1]) + wa2 * src[ia2];
            dst[n] = v;
        }
    }
}

extern "C" void kernel_launch(void* const* d_in, const int* in_sizes, int n_in,
                              void* d_out, int out_size, void* d_ws, size_t ws_size,
                              hipStream_t stream) {
    const float* coords     = (const float*)d_in[0];
    const float* ref_coords = (const float*)d_in[1];
    const float* refF       = (const float*)d_in[2];
    const float* refT       = (const float*)d_in[3];
    const float* pf         = (const float*)d_in[4];
    float* out = (float*)d_out;

    hipLaunchKernelGGL(fp_fused_kernel, dim3(NN / NPB, BB), dim3(256), 0, stream,
                       coords, ref_coords, refF, refT, pf, out);
}

// Round 7
// 228.415 us; speedup vs baseline: 1.2585x; 1.2585x over previous
//
#include <hip/hip_runtime.h>
#include <cstdint>

#define BB 2
#define NN 16384
#define MM 4096
#define CF 256
#define CT 128
#define CP 64
#define NPB 64      // query points per block (grid stays 512 -> FETCH stays low)
#define CHUNK 2048  // ref points staged in LDS per pass (32 KB)
#define TPB 512     // 8 waves/block, 2 blocks/CU -> 16 waves/CU resident

// All-FP32 fused kernel. Phase 1: exact 3-NN — numpy-bit-exact fp32
// (contraction off, numpy association order, stable lower-index tie-break),
// 8 sub-lanes per query point. Phase 2: gather-interp + skip concat.
// Structure = round-3's proven 171us kernel with TPB 256->512 (occupancy via
// waves-per-block, NOT block count — round 6 showed more blocks doubles
// per-block restaging FETCH traffic and regresses).
__global__ __launch_bounds__(TPB, 4) void fp_fused_kernel(
    const float* __restrict__ coords,      // [B,N,3]
    const float* __restrict__ ref_coords,  // [B,M,3]
    const float* __restrict__ refF,        // [B,256,M]
    const float* __restrict__ refT,        // [B,128,M]
    const float* __restrict__ pf,          // [B,64,N]
    float* __restrict__ out)               // [B,320,N] ++ [B,128,N]
{
#pragma clang fp contract(off)
    __shared__ float4 refs[CHUNK];      // 32 KB (x, y, z, rr)
    __shared__ int    s_idx[NPB * 3];
    __shared__ float  s_w[NPB * 3];

    const int tid = threadIdx.x;
    const int b   = blockIdx.y;
    const int n0  = blockIdx.x * NPB;

    // ---------------- phase 1: 3-NN, 8 lanes per query point ----------------
    const int pl = tid >> 3;            // point-in-block 0..63
    const int s  = tid & 7;             // sub-lane 0..7
    const int n  = n0 + pl;

    const float* cp = coords + ((size_t)b * NN + n) * 3;
    const float cx = cp[0];
    const float cy = cp[1];
    const float cz = cp[2];
    const float cc = (cx * cx + cy * cy) + cz * cz;   // numpy sum order

    float d0 = INFINITY, d1 = INFINITY, d2v = INFINITY;
    int   i0 = 0, i1 = 0, i2 = 0;       // benign fallbacks (no sentinels)

    const float* rc = ref_coords + (size_t)b * MM * 3;

    for (int ch = 0; ch < MM / CHUNK; ++ch) {
        __syncthreads();                 // refs[] reuse guard
        for (int e = tid; e < CHUNK; e += TPB) {
            const int j = ch * CHUNK + e;
            const float x = rc[3 * j + 0];
            const float y = rc[3 * j + 1];
            const float z = rc[3 * j + 2];
            refs[e] = make_float4(x, y, z, (x * x + y * y) + z * z);
        }
        __syncthreads();

        // lane scans e = s, s+8, ... ascending -> strict '<' keeps lowest idx
        #pragma unroll 4
        for (int it = 0; it < CHUNK / 8; ++it) {
            const int e = s + (it << 3);
            const float4 r = refs[e];
            const float t  = (cx * r.x + cy * r.y) + cz * r.z;  // einsum order
            const float dd = (cc + r.w) - (t + t);              // (A+B)-2*dot
            const int j = ch * CHUNK + e;
            const bool l2 = dd < d2v;
            const bool l1 = dd < d1;
            const bool l0 = dd < d0;
            d2v = l2 ? (l1 ? d1 : dd) : d2v;  i2 = l2 ? (l1 ? i1 : j) : i2;
            d1  = l1 ? (l0 ? d0 : dd) : d1;   i1 = l1 ? (l0 ? i0 : j) : i1;
            d0  = l0 ? dd : d0;               i0 = l0 ? j  : i0;
        }
    }

    // lexicographic (d, idx) insert: lower index wins exact ties (stable top_k)
    auto ins = [&](float e, int f) {
        const bool l2 = (e < d2v) || (e == d2v && f < i2);
        const bool l1 = (e < d1)  || (e == d1  && f < i1);
        const bool l0 = (e < d0)  || (e == d0  && f < i0);
        d2v = l2 ? (l1 ? d1 : e) : d2v;  i2 = l2 ? (l1 ? i1 : f) : i2;
        d1  = l1 ? (l0 ? d0 : e) : d1;   i1 = l1 ? (l0 ? i0 : f) : i1;
        d0  = l0 ? e : d0;               i0 = l0 ? f : i0;
    };

    // butterfly across the 8 sub-lanes (xor<8 stays in-group, in-wave)
    for (int off = 1; off < 8; off <<= 1) {
        const float e0 = __shfl_xor(d0,  off, 64);
        const float e1 = __shfl_xor(d1,  off, 64);
        const float e2 = __shfl_xor(d2v, off, 64);
        const int   f0 = __shfl_xor(i0,  off, 64);
        const int   f1 = __shfl_xor(i1,  off, 64);
        const int   f2 = __shfl_xor(i2,  off, 64);
        ins(e0, f0);
        ins(e1, f1);
        ins(e2, f2);
    }

    if (s == 0) {
        float w0 = 1.0f / (d0  + 1e-8f);     // IEEE divs, numpy order
        float w1 = 1.0f / (d1  + 1e-8f);
        float w2 = 1.0f / (d2v + 1e-8f);
        const float sum = (w0 + w1) + w2;
        s_idx[pl * 3 + 0] = i0;
        s_idx[pl * 3 + 1] = i1;
        s_idx[pl * 3 + 2] = i2;
        s_w[pl * 3 + 0] = w0 / sum;
        s_w[pl * 3 + 1] = w1 / sum;
        s_w[pl * 3 + 2] = w2 / sum;
    }
    __syncthreads();

    // ---------------- phase 2: interpolate + concat ----------------
    // 16 groups of 32 lanes; group g handles rows g, g+16, ... (448 rows).
    // Class boundaries (256, 320) are multiples of 16 -> uniform branches.
    const int g  = tid >> 5;
    const int l  = tid & 31;
    const int p0 = 2 * l;

    auto clampi = [](int v) { return v < 0 ? 0 : (v > MM - 1 ? MM - 1 : v); };
    const int   ia0 = clampi(s_idx[p0 * 3 + 0]);
    const int   ia1 = clampi(s_idx[p0 * 3 + 1]);
    const int   ia2 = clampi(s_idx[p0 * 3 + 2]);
    const int   ib0 = clampi(s_idx[p0 * 3 + 3]);
    const int   ib1 = clampi(s_idx[p0 * 3 + 4]);
    const int   ib2 = clampi(s_idx[p0 * 3 + 5]);
    const float wa0 = s_w[p0 * 3 + 0], wa1 = s_w[p0 * 3 + 1], wa2 = s_w[p0 * 3 + 2];
    const float wb0 = s_w[p0 * 3 + 3], wb1 = s_w[p0 * 3 + 4], wb2 = s_w[p0 * 3 + 5];

    const size_t outT_base = (size_t)BB * (CF + CP) * NN;

    for (int it = 0; it < (CF + CP + CT) / 16; ++it) {
        const int row = it * 16 + g;
        if (row < CF) {
            const float* src = refF + ((size_t)b * CF + row) * MM;
            float* dst = out + ((size_t)b * (CF + CP) + row) * NN + n0;
            const float v0 = (wa0 * src[ia0] + wa1 * src[ia1]) + wa2 * src[ia2];
            const float v1 = (wb0 * src[ib0] + wb1 * src[ib1]) + wb2 * src[ib2];
            float2 pr; pr.x = v0; pr.y = v1;
            *reinterpret_cast<float2*>(dst + p0) = pr;
        } else if (row < CF + CP) {
            const float* src = pf + ((size_t)b * CP + (row - CF)) * NN + n0;
            float* dst = out + ((size_t)b * (CF + CP) + row) * NN + n0;
            *reinterpret_cast<float2*>(dst + p0) =
                *reinterpret_cast<const float2*>(src + p0);
        } else {
            const int tr = row - (CF + CP);
            const float* src = refT + ((size_t)b * CT + tr) * MM;
            float* dst = out + outT_base + ((size_t)b * CT + tr) * NN + n0;
            const float v0 = (wa0 * src[ia0] + wa1 * src[ia1]) + wa2 * src[ia2];
            const float v1 = (wb0 * src[ib0] + wb1 * src[ib1]) + wb2 * src[ib2];
            float2 pr; pr.x = v0; pr.y = v1;
            *reinterpret_cast<float2*>(dst + p0) = pr;
        }
    }
}

extern "C" void kernel_launch(void* const* d_in, const int* in_sizes, int n_in,
                              void* d_out, int out_size, void* d_ws, size_t ws_size,
                              hipStream_t stream) {
    const float* coords     = (const float*)d_in[0];
    const float* ref_coords = (const float*)d_in[1];
    const float* refF       = (const float*)d_in[2];
    const float* refT       = (const float*)d_in[3];
    const float* pf         = (const float*)d_in[4];
    float* out = (float*)d_out;

    hipLaunchKernelGGL(fp_fused_kernel, dim3(NN / NPB, BB), dim3(TPB), 0, stream,
                       coords, ref_coords, refF, refT, pf, out);
}